// Round 5
// baseline (670.087 us; speedup 1.0000x reference)
//
#include <hip/hip_runtime.h>

// Problem constants (from setup_inputs):
//   input_: (B=64, 2*N=16384, 2, 2, D1=16) f32
//   diag1/diag2: (N=8192, 2, 2, D2=8) f32
//   out: (B, N, 2, 2, DOUT=23) f32,  out[b,n,i,j,:] =
//        sum_k conv(x1[b,n,i,k,:], d1[n,k,j,:]) + sum_k conv(x2[b,n,i,k,:], d2[n,k,j,:])
//
// Round 5: one thread per (b, n, i, j) -> live set = acc(23)+x(16)+d(8)+addr
// ~= 57 regs, capped at VGPR=64 via __launch_bounds__(256,8) to get ABOVE the
// 64-reg occupancy cliff: 8 waves/SIMD (round 4: VGPR=120 -> 4 waves/SIMD,
// latency-bound at 2.3 TB/s; round 3 proved 64-reg waves sustain 3.5+ TB/s).
// Round-3 spill trap avoided because the live set genuinely fits this time.
#define BB 64
#define NN 8192
#define D1C 16
#define D2C 8
#define DOUT 23

// One segment: fixed (half, k, j). xp -> 16 floats x[b,n,i,k,:],
// dp -> 8 floats d[n,k,j,:]. acc[u+v] += x[u]*d[v].
__device__ __forceinline__ void seg(const float4* __restrict__ xp,
                                    const float4* __restrict__ dp,
                                    float acc[DOUT]) {
    float4 xq0 = xp[0], xq1 = xp[1], xq2 = xp[2], xq3 = xp[3];
    float4 dq0 = dp[0], dq1 = dp[1];

    float xv[D1C] = {xq0.x, xq0.y, xq0.z, xq0.w, xq1.x, xq1.y, xq1.z, xq1.w,
                     xq2.x, xq2.y, xq2.z, xq2.w, xq3.x, xq3.y, xq3.z, xq3.w};
    float dv[D2C] = {dq0.x, dq0.y, dq0.z, dq0.w, dq1.x, dq1.y, dq1.z, dq1.w};

#pragma unroll
    for (int v = 0; v < D2C; ++v) {
        const float c = dv[v];
#pragma unroll
        for (int u = 0; u < D1C; ++u) {
            acc[u + v] += xv[u] * c;
        }
    }
}

__global__ __launch_bounds__(256, 8) void hstackdiag_kernel(
    const float* __restrict__ input,
    const float* __restrict__ diag1,
    const float* __restrict__ diag2,
    float* __restrict__ out) {
    const int t = blockIdx.x * blockDim.x + threadIdx.x;  // linear (b, n, i, j)
    const int j = t & 1;
    const int i = (t >> 1) & 1;
    const int n = (t >> 2) & (NN - 1);
    const int b = t >> 15;

    // x[b][n][i][k][u] (half 1): float4 offset b*2N*16 + n*16 + i*8 + k*4
    const float4* xh = (const float4*)input +
                       (size_t)b * (2 * NN) * 16 + (size_t)n * 16 + (size_t)i * 8;
    // d[n][k][j][v]: float4 offset n*8 + k*4 + j*2
    const float4* dh1 = (const float4*)diag1 + (size_t)n * 8 + (size_t)j * 2;
    const float4* dh2 = (const float4*)diag2 + (size_t)n * 8 + (size_t)j * 2;

    float acc[DOUT];
#pragma unroll
    for (int u = 0; u < DOUT; ++u) acc[u] = 0.0f;

    seg(xh + 0, dh1 + 0, acc);                // half 1, k=0
    seg(xh + 4, dh1 + 4, acc);                // half 1, k=1
    seg(xh + (size_t)NN * 16 + 0, dh2 + 0, acc);  // half 2, k=0
    seg(xh + (size_t)NN * 16 + 4, dh2 + 4, acc);  // half 2, k=1

    // out[b][n][i][j][:]: flat float offset t*23. 92 B/lane stride; scalar
    // stores, L2 write-combining merges adjacent lanes into full lines.
    float* o = out + (size_t)t * DOUT;
#pragma unroll
    for (int q = 0; q < DOUT; ++q) {
        o[q] = acc[q];
    }
}

extern "C" void kernel_launch(void* const* d_in, const int* in_sizes, int n_in,
                              void* d_out, int out_size, void* d_ws, size_t ws_size,
                              hipStream_t stream) {
    const float* input = (const float*)d_in[0];
    const float* diag1 = (const float*)d_in[1];
    const float* diag2 = (const float*)d_in[2];
    float* out = (float*)d_out;

    const int total = BB * NN * 2 * 2;   // 2,097,152 threads, one per (b,n,i,j)
    const int block = 256;
    const int grid = total / block;      // 8192 blocks, exact
    hstackdiag_kernel<<<grid, block, 0, stream>>>(input, diag1, diag2, out);
}

// Round 6
// 87.860 us; speedup vs baseline: 7.6268x; 7.6268x over previous
//
#include <hip/hip_runtime.h>

// input_: (B=64, 2*N=16384, 2, 2, 16) f32 ; diag1/2: (N=8192, 2, 2, 8) f32
// out: (B, N, 2, 2, 23) f32
//   out[b,n,i,j,:] = sum_k conv(x1[b,n,i,k,:], d1[n,k,j,:]) + (x2, d2)
//
// Round 6: block-tiled LDS design. Rounds 3/5 proved launch_bounds min-wave
// hints cause catastrophic spills; rounds 2-5 proved the op is TLP-latency-
// bound (BW rises monotonically with occupancy). So: guarantee small live set
// structurally. Block = 64 (b,n) units; x-tiles reg-staged to LDS (coalesced,
// 8 indep loads/thread), XOR-swizzled chunks (read pattern = T2's column-read
// conflict, 8x penalty unswizzled); compute thread=(unit,i,j) keeps only
// acc[23]+x[16]+d[8]; output staged through LDS for full-line coalesced stores.
#define BB 64
#define NN 8192
#define TILE 64
#define DOUT 23

__global__ __launch_bounds__(256) void hstackdiag_kernel(
    const float* __restrict__ input,
    const float* __restrict__ diag1,
    const float* __restrict__ diag2,
    float* __restrict__ out) {
    __shared__ float4 sbuf[2048];  // 32 KB: x1 chunks [0,1024), x2 [1024,2048)

    const int t = threadIdx.x;
    const int bx = blockIdx.x;
    const int b = bx >> 7;              // 128 ntiles per b
    const int n0 = (bx & 127) * TILE;

    // ---- stage x1/x2 tiles (16 KB each) into LDS, swizzled ----
    // global tile is contiguous: 64 units x 64 floats = 1024 float4 chunks.
    const float4* g1 = (const float4*)input + ((size_t)b * (2 * NN) + n0) * 16;
    const float4* g2 = g1 + (size_t)NN * 16;

    float4 r1[4], r2[4];
#pragma unroll
    for (int r = 0; r < 4; ++r) r1[r] = g1[r * 256 + t];
#pragma unroll
    for (int r = 0; r < 4; ++r) r2[r] = g2[r * 256 + t];
#pragma unroll
    for (int r = 0; r < 4; ++r) {
        const int G = r * 256 + t;
        const int L = G ^ ((G >> 3) & 7);   // involution; bank-spreads columns
        sbuf[L] = r1[r];
    }
#pragma unroll
    for (int r = 0; r < 4; ++r) {
        const int G = r * 256 + t;
        const int L = G ^ ((G >> 3) & 7);
        sbuf[1024 + L] = r2[r];
    }
    __syncthreads();

    // ---- compute: thread = (unit, i, j) ----
    const int j = t & 1;
    const int i = (t >> 1) & 1;
    const int unit = t >> 2;
    const int n = n0 + unit;

    // d[n][k][j][v]: float4 index n*8 + k*4 + j*2
    const float4* dp1 = (const float4*)diag1 + (size_t)n * 8 + j * 2;
    const float4* dp2 = (const float4*)diag2 + (size_t)n * 8 + j * 2;

    float acc[DOUT];
#pragma unroll
    for (int u = 0; u < DOUT; ++u) acc[u] = 0.0f;

#pragma unroll
    for (int h = 0; h < 2; ++h) {
        const int sb = h * 1024;
        const float4* dp = (h == 0) ? dp1 : dp2;
#pragma unroll
        for (int k = 0; k < 2; ++k) {
            float4 dq0 = dp[k * 4 + 0];
            float4 dq1 = dp[k * 4 + 1];
            float dv[8] = {dq0.x, dq0.y, dq0.z, dq0.w,
                           dq1.x, dq1.y, dq1.z, dq1.w};

            float xv[16];
#pragma unroll
            for (int q = 0; q < 4; ++q) {
                const int Gc = unit * 16 + i * 8 + k * 4 + q;
                const int Lc = Gc ^ ((Gc >> 3) & 7);
                float4 xq = sbuf[sb + Lc];
                xv[q * 4 + 0] = xq.x;
                xv[q * 4 + 1] = xq.y;
                xv[q * 4 + 2] = xq.z;
                xv[q * 4 + 3] = xq.w;
            }
#pragma unroll
            for (int v = 0; v < 8; ++v) {
                const float c = dv[v];
#pragma unroll
                for (int u = 0; u < 16; ++u) {
                    acc[u + v] += xv[u] * c;
                }
            }
        }
    }

    // ---- output: stage tile in LDS, then fully-coalesced stores ----
    __syncthreads();  // done reading sbuf
    float* sout = (float*)sbuf;  // 64 units * 92 floats = 23552 B < 32 KB
#pragma unroll
    for (int q = 0; q < DOUT; ++q) {
        sout[t * DOUT + q] = acc[q];  // bank = (23t+q)%32: 2 lanes/bank, free
    }
    __syncthreads();
    float* gout = out + ((size_t)b * NN + n0) * (4 * DOUT);  // contiguous tile
#pragma unroll
    for (int r = 0; r < DOUT; ++r) {
        gout[r * 256 + t] = sout[r * 256 + t];  // 1 KB/wave-instr, full lines
    }
}

extern "C" void kernel_launch(void* const* d_in, const int* in_sizes, int n_in,
                              void* d_out, int out_size, void* d_ws, size_t ws_size,
                              hipStream_t stream) {
    const float* input = (const float*)d_in[0];
    const float* diag1 = (const float*)d_in[1];
    const float* diag2 = (const float*)d_in[2];
    float* out = (float*)d_out;

    const int grid = BB * (NN / TILE);   // 64 * 128 = 8192 blocks
    hstackdiag_kernel<<<grid, 256, 0, stream>>>(input, diag1, diag2, out);
}